// Round 10
// baseline (157.558 us; speedup 1.0000x reference)
//
#include <hip/hip_runtime.h>
#include <hip/hip_bf16.h>

// RNN_73048803770905: fused [B,T,200]x[200,64] projection + 128-step tanh RNN + sigmoid head.
// B=4096, T=128, D_IN=200, H=64. 419 MB x read once; HBM floor ~67us.
// R9: R8 (passing, independent waves, acc-as-C, zero in-loop barriers) with the grid
// FIXED: 1024 blocks at exactly 4 blocks/CU (launch_bounds(256,4), 4 waves/SIMD, one
// generation, no tail). VGPR diet to fit 128: px split pA(ks0-3)/pB(ks4-6), cvt8 inline
// (transient frag), LOADB at chunk start, only pA in flight across the 16-step phase,
// Wout read in epilogue. All numerics/logic identical to R8's verified version.

#define TSEQ 128
#define DIN  200
#define HID  64
#define CT   16
#define NCH  (TSEQ/CT)   // 8

typedef short bf16x8 __attribute__((ext_vector_type(8)));
typedef float f32x4  __attribute__((ext_vector_type(4)));

__device__ __forceinline__ unsigned short f2bf(float f) {
  __hip_bfloat16 h = __float2bfloat16(f);
  return __builtin_bit_cast(unsigned short, h);
}
__device__ __forceinline__ bf16x8 cvt8(f32x4 a, f32x4 b) {
  bf16x8 r;
#pragma unroll
  for (int i = 0; i < 4; ++i) { r[i] = (short)f2bf(a[i]); r[4 + i] = (short)f2bf(b[i]); }
  return r;
}
// tanh(x) = 1 - 2/(1 + 2^(x*2/ln2)); v_exp_f32 handles the extremes.
__device__ __forceinline__ float tanh_fast(float x) {
  float e = exp2f(x * 2.885390081777927f);
  float r = __builtin_amdgcn_rcpf(1.f + e);
  return __builtin_fmaf(-2.f, r, 1.f);
}

__global__ __launch_bounds__(256, 4) void rnn_fused(
    const float* __restrict__ x,   const float* __restrict__ Wih,
    const float* __restrict__ Whh, const float* __restrict__ bih,
    const float* __restrict__ bhh, const float* __restrict__ Wout,
    const float* __restrict__ bout, float* __restrict__ out)
{
  __shared__ unsigned short wihL[28][64][8];   // Wih bf16 frags, shared: 28 KB
  __shared__ unsigned short hb[4][2][80];      // per-wave h double buffer: 1.25 KB

  const int tid  = threadIdx.x;
  const int w    = tid >> 6;
  const int lane = tid & 63;
  const int m    = lane & 15;
  const int g    = lane >> 4;
  const int row  = blockIdx.x * 4 + w;         // 1024 blocks, 1 batch row per wave

  // A-frag loads: lane (g,m) holds x[row][t = 16c + m][k = ks*32 + g*8 + j].
  const float* xl = x + ((size_t)row * TSEQ + m) * DIN;

  f32x4 pA[4][2], pB[3][2];
  auto LOADA = [&](int c) {   // ks 0..3 (32 VGPR) - long-flight batch, lives across steps
    const float* p = xl + (size_t)c * (CT * DIN);
#pragma unroll
    for (int ks = 0; ks < 4; ++ks) {
      const int d = ks * 32 + g * 8;
      pA[ks][0] = *reinterpret_cast<const f32x4*>(p + d);
      pA[ks][1] = *reinterpret_cast<const f32x4*>(p + d + 4);
    }
  };
  auto LOADB = [&](int c) {   // ks 4..6 (24 VGPR) - issued at chunk start, consumed same chunk
    const float* p = xl + (size_t)c * (CT * DIN);
#pragma unroll
    for (int ks = 4; ks < 6; ++ks) {
      const int d = ks * 32 + g * 8;
      pB[ks - 4][0] = *reinterpret_cast<const f32x4*>(p + d);
      pB[ks - 4][1] = *reinterpret_cast<const f32x4*>(p + d + 4);
    }
    pB[2][0] = *reinterpret_cast<const f32x4*>(p + 192);   // tail d=192..199, all lanes
    pB[2][1] = *reinterpret_cast<const f32x4*>(p + 196);   // (zeroed at cvt for g>0)
  };
  LOADA(0);   // chunk 0 ks0-3 in flight during init

  // ---- shared Wih frags: frag f = nt*7+ks; lane = Wih[nt*16+m][ks*32+g*8..+7]
  for (int f = w; f < 28; f += 4) {
    const int nt = f / 7, ks = f % 7;
    const int d  = ks * 32 + g * 8;
    bf16x8 v = (bf16x8)0;
    if (d + 8 <= DIN) {
      const float* wr = Wih + (size_t)(nt * 16 + m) * DIN + d;
      v = cvt8(*reinterpret_cast<const f32x4*>(wr), *reinterpret_cast<const f32x4*>(wr + 4));
    }
    *reinterpret_cast<bf16x8*>(&wihL[f][lane][0]) = v;
  }

  // ---- Whh frags in regs (32 VGPR): B[k][n=h], lane n = nt*16+m, k = hf*32+g*8+j
  bf16x8 whhf[4][2];
#pragma unroll
  for (int nt = 0; nt < 4; ++nt)
#pragma unroll
    for (int hf = 0; hf < 2; ++hf) {
      const float* wr = Whh + (size_t)(nt * 16 + m) * HID + hf * 32 + g * 8;
      whhf[nt][hf] = cvt8(*reinterpret_cast<const f32x4*>(wr),
                          *reinterpret_cast<const f32x4*>(wr + 4));
    }
  float biasv[4];
#pragma unroll
  for (int nt = 0; nt < 4; ++nt) biasv[nt] = bih[nt * 16 + m] + bhh[nt * 16 + m];

  hb[w][0][lane] = 0;   // h_{-1} = 0; t=0 reads buf 1
  hb[w][1][lane] = 0;
  __syncthreads();      // wihL ready; ONLY barrier in the kernel

  float vfin[4] = {0.f, 0.f, 0.f, 0.f};   // final h, valid on g==3 lanes

  for (int c = 0; c < NCH; ++c) {
    LOADB(c);   // ks4-6 of current chunk; latency hides under ks0-3 cvt+MFMA

    // ---- proj: acc = x_tile * Wih^T + bias; 16 D rows = 16 timesteps; acc stays as C
    f32x4 acc[4];
#pragma unroll
    for (int nt = 0; nt < 4; ++nt) acc[nt] = (f32x4)(biasv[nt]);
#pragma unroll
    for (int ks = 0; ks < 4; ++ks) {
      const bf16x8 a = cvt8(pA[ks][0], pA[ks][1]);   // vmcnt wait for pA(c) lands here
#pragma unroll
      for (int nt = 0; nt < 4; ++nt) {
        bf16x8 bv = *reinterpret_cast<const bf16x8*>(&wihL[nt * 7 + ks][lane][0]);
        acc[nt] = __builtin_amdgcn_mfma_f32_16x16x32_bf16(a, bv, acc[nt], 0, 0, 0);
      }
    }
    if (c + 1 < NCH) LOADA(c + 1);   // pA free; in flight across ks4-6 + all 16 steps
#pragma unroll
    for (int ks = 4; ks < 7; ++ks) {
      const bf16x8 a = (ks < 6) ? cvt8(pB[ks - 4][0], pB[ks - 4][1])
                                : ((g == 0) ? cvt8(pB[2][0], pB[2][1]) : (bf16x8)0);
#pragma unroll
      for (int nt = 0; nt < 4; ++nt) {
        bf16x8 bv = *reinterpret_cast<const bf16x8*>(&wihL[nt * 7 + ks][lane][0]);
        acc[nt] = __builtin_amdgcn_mfma_f32_16x16x32_bf16(a, bv, acc[nt], 0, 0, 0);
      }
    }

    // ---- 16 recurrence steps, fully in-wave (R8-verified). A = h_{t-1} broadcast to
    // all 16 rows (uniform conflict-free ds_read); D row s valid at g = s>>2, reg s&3.
#pragma unroll
    for (int s = 0; s < CT; ++s) {
      const int rb = s & 1, pb = rb ^ 1;   // compile-time parity (CT even)
      asm volatile("" ::: "memory");       // fence: no reordering of h LDS ops
      bf16x8 ha0 = *reinterpret_cast<const bf16x8*>(&hb[w][pb][g * 8]);        // k 0..31
      bf16x8 ha1 = *reinterpret_cast<const bf16x8*>(&hb[w][pb][32 + g * 8]);   // k 32..63
      f32x4 racc[4];
#pragma unroll
      for (int nt = 0; nt < 4; ++nt)
        racc[nt] = __builtin_amdgcn_mfma_f32_16x16x32_bf16(ha0, whhf[nt][0], acc[nt], 0, 0, 0);
#pragma unroll
      for (int nt = 0; nt < 4; ++nt)
        racc[nt] = __builtin_amdgcn_mfma_f32_16x16x32_bf16(ha1, whhf[nt][1], racc[nt], 0, 0, 0);
      if (g == (s >> 2)) {                 // the one group holding D row s
#pragma unroll
        for (int nt = 0; nt < 4; ++nt) {
          const float v = tanh_fast(racc[nt][s & 3]);
          hb[w][rb][nt * 16 + m] = f2bf(v);          // 16 lanes x 4 cols = all 64
          if (s == CT - 1) vfin[nt] = v;
        }
      }
      asm volatile("" ::: "memory");
    }
  }

  // ---- epilogue: g==3 lanes hold final h; reduce within the 16-lane group
  float sred = vfin[0] * Wout[m]      + vfin[1] * Wout[16 + m]
             + vfin[2] * Wout[32 + m] + vfin[3] * Wout[48 + m];
  sred += __shfl_xor(sred, 1, 64);
  sred += __shfl_xor(sred, 2, 64);
  sred += __shfl_xor(sred, 4, 64);
  sred += __shfl_xor(sred, 8, 64);
  if (lane == 48)
    out[row] = __builtin_amdgcn_rcpf(1.f + exp2f(-(sred + bout[0]) * 1.4426950408889634f));
}

extern "C" void kernel_launch(void* const* d_in, const int* in_sizes, int n_in,
                              void* d_out, int out_size, void* d_ws, size_t ws_size,
                              hipStream_t stream) {
  const float* x    = (const float*)d_in[0];
  const float* Wih  = (const float*)d_in[1];
  const float* Whh  = (const float*)d_in[2];
  const float* bih  = (const float*)d_in[3];
  const float* bhh  = (const float*)d_in[4];
  const float* Wout = (const float*)d_in[5];
  const float* bout = (const float*)d_in[6];
  float* out = (float*)d_out;

  const int B = in_sizes[0] / (TSEQ * DIN);   // 4096
  rnn_fused<<<dim3(B / 4), dim3(256), 0, stream>>>(x, Wih, Whh, bih, bhh, Wout, bout, out);
}

// Round 11
// 97.955 us; speedup vs baseline: 1.6085x; 1.6085x over previous
//
#include <hip/hip_runtime.h>
#include <hip/hip_bf16.h>

// RNN_73048803770905: fused [B,T,200]x[200,64] projection + 128-step tanh RNN + sigmoid head.
// B=4096, T=128, D_IN=200, H=64. 419 MB x read once.
// R10 = R5 restored (best: 98.4us, 4.26 TB/s effective read). Six independent designs
// (R1-R9) all land at 4.1-4.45 TB/s read -> empirical read-only stream ceiling ~4.4 TB/s
// (fills write at 6.9; the 6.3 "copy" ubench is read+write summed). R5 sits at ~97% of it.
// Structure: global_load_lds f32 staging, double-buffered, counted vmcnt (steady vmcnt(8),
// never 0 mid-loop) so loads stay in flight across raw s_barriers. Block = 8 rows,
// 512 blocks, 2 blocks/CU. Cooperative proj (wave w owns t=4c+w) + recurrence
// (wave w owns h-cols w*16..w*16+15).

#define TSEQ 128
#define DIN  200
#define HID  64
#define NB   8
#define TC   4
#define NCH  (TSEQ/TC)
#define RSTRIDE 804   // floats per stage row: 4*200 + 4 pad (16B-aligned, bank-spread)

typedef short bf16x8 __attribute__((ext_vector_type(8)));
typedef float f32x4  __attribute__((ext_vector_type(4)));
typedef const __attribute__((address_space(1))) unsigned int GU32;
typedef __attribute__((address_space(3))) unsigned int LU32;

__device__ __forceinline__ unsigned short f2bf(float f) {
  __hip_bfloat16 h = __float2bfloat16(f);
  return __builtin_bit_cast(unsigned short, h);
}
__device__ __forceinline__ bf16x8 cvt8(f32x4 a, f32x4 b) {
  bf16x8 r;
#pragma unroll
  for (int i = 0; i < 4; ++i) { r[i] = (short)f2bf(a[i]); r[4 + i] = (short)f2bf(b[i]); }
  return r;
}
// tanh(x) = 1 - 2/(1 + 2^(x*2/ln2)); v_exp_f32 handles the extremes.
__device__ __forceinline__ float tanh_fast(float x) {
  float e = exp2f(x * 2.885390081777927f);
  float r = __builtin_amdgcn_rcpf(1.f + e);
  return __builtin_fmaf(-2.f, r, 1.f);
}
// LDS-only barrier: does NOT drain vmcnt -> staged loads stay in flight.
__device__ __forceinline__ void barrier_lds() {
  asm volatile("s_waitcnt lgkmcnt(0)" ::: "memory");
  __builtin_amdgcn_s_barrier();
  __builtin_amdgcn_sched_barrier(0);
}
__device__ __forceinline__ void wait_vm8() {
  asm volatile("s_waitcnt vmcnt(8)" ::: "memory");
  __builtin_amdgcn_sched_barrier(0);
}
__device__ __forceinline__ void wait_vm0() {
  asm volatile("s_waitcnt vmcnt(0)" ::: "memory");
  __builtin_amdgcn_sched_barrier(0);
}

__global__ __launch_bounds__(256, 2) void rnn_fused(
    const float* __restrict__ x,   const float* __restrict__ Wih,
    const float* __restrict__ Whh, const float* __restrict__ bih,
    const float* __restrict__ bhh, const float* __restrict__ Wout,
    const float* __restrict__ bout, float* __restrict__ out)
{
  __shared__ float          stg[2][NB][RSTRIDE];   // x f32 stage, dbuf: 51456 B
  __shared__ float          xp[TC][NB][68];        // xp chunk f32 (+ final h): 8704 B
  __shared__ unsigned short hbuf[2][16][72];       // h dbuf bf16 bits: 4608 B  (63.3 KB total)

  const int tid  = threadIdx.x;
  const int w    = tid >> 6;
  const int lane = tid & 63;
  const int m    = lane & 15;
  const int g    = lane >> 4;
  const int b0   = blockIdx.x * NB;

  // ---- weights into registers (all global loads BEFORE the staged-load stream) ----
  bf16x8 wihf[4][7];   // B[k=d][n=h]: lane h = nt*16+m, d = ks*32+g*8+j
#pragma unroll
  for (int nt = 0; nt < 4; ++nt) {
    const float* wr = Wih + (size_t)(nt * 16 + m) * DIN;
#pragma unroll
    for (int ks = 0; ks < 7; ++ks) {
      const int d = ks * 32 + g * 8;
      if (d + 8 <= DIN)
        wihf[nt][ks] = cvt8(*reinterpret_cast<const f32x4*>(wr + d),
                            *reinterpret_cast<const f32x4*>(wr + d + 4));
      else
        wihf[nt][ks] = (bf16x8)0;
    }
  }
  bf16x8 whhf[2];      // B[k][n=h]: wave owns n-tile w (h = w*16+m), k = hf*32+g*8+j
#pragma unroll
  for (int hf = 0; hf < 2; ++hf) {
    const float* wr = Whh + (size_t)(w * 16 + m) * HID + hf * 32 + g * 8;
    whhf[hf] = cvt8(*reinterpret_cast<const f32x4*>(wr),
                    *reinterpret_cast<const f32x4*>(wr + 4));
  }
  float biasv[4];
#pragma unroll
  for (int nt = 0; nt < 4; ++nt) biasv[nt] = bih[nt * 16 + m] + bhh[nt * 16 + m];

  // ensure no weight load is still outstanding (keeps vmcnt arithmetic exact)
  wait_vm0();

  // ---- staged loads: wave w owns rows {2w, 2w+1}; 8 global_load_lds per chunk ----
  auto LOADC = [&](int buf, int c) {
#pragma unroll
    for (int r = 0; r < 2; ++r) {
      const int row = w * 2 + r;
      const float* gb = x + (size_t)(b0 + row) * (TSEQ * DIN) + (size_t)c * (TC * DIN);
      float* lb = &stg[buf][row][0];
#pragma unroll
      for (int i = 0; i < 3; ++i)
        __builtin_amdgcn_global_load_lds((GU32*)(gb + i * 256 + lane * 4),
                                         (LU32*)(lb + i * 256), 16, 0, 0);
      if (lane < 8)
        __builtin_amdgcn_global_load_lds((GU32*)(gb + 768 + lane * 4),
                                         (LU32*)(lb + 768), 16, 0, 0);
    }
  };
  LOADC(0, 0);
  LOADC(1, 1);

  // zero h state (h_{-1} = 0)
  for (int i = tid; i < 2 * 16 * 72 / 2; i += 256)
    reinterpret_cast<unsigned int*>(&hbuf[0][0][0])[i] = 0u;

  for (int c = 0; c < NCH; ++c) {
    const int buf = c & 1;
    // (1) chunk c landed for THIS wave (8 newest = chunk c+1 stay in flight), then all waves
    if (c + 1 < NCH) wait_vm8(); else wait_vm0();
    __builtin_amdgcn_s_barrier();
    __builtin_amdgcn_sched_barrier(0);

    // (2) A-frags from stage: row m (rows 8-15 garbage, row-local, discarded), t = w
    bf16x8 afr[7];
    {
      const float* sp = &stg[buf][0][0];
#pragma unroll
      for (int ks = 0; ks < 7; ++ks) {
        const int off = m * RSTRIDE + w * 200 + (ks < 6 ? ks * 32 + g * 8 : 192);
        afr[ks] = cvt8(*reinterpret_cast<const f32x4*>(sp + off),
                       *reinterpret_cast<const f32x4*>(sp + off + 4));
      }
      if (g != 0) afr[6] = (bf16x8)0;   // k >= 200 tail
    }
    barrier_lds();   // all waves done reading stg[buf]

    // (3) refill stg[buf] with chunk c+2 (in flight through proj + 4 steps)
    if (c + 2 < NCH) LOADC(buf, c + 2);

    // (4) proj: xp(t=4c+w) = x_t * Wih^T + bias
    f32x4 acc[4];
#pragma unroll
    for (int nt = 0; nt < 4; ++nt) acc[nt] = (f32x4)(biasv[nt]);
#pragma unroll
    for (int ks = 0; ks < 7; ++ks)
#pragma unroll
      for (int nt = 0; nt < 4; ++nt)
        acc[nt] = __builtin_amdgcn_mfma_f32_16x16x32_bf16(afr[ks], wihf[nt][ks], acc[nt], 0, 0, 0);
    // D: col = lane&15, row = g*4+rr (valid rows 0-7 <=> g<2)
    if (g < 2) {
#pragma unroll
      for (int nt = 0; nt < 4; ++nt)
#pragma unroll
        for (int rr = 0; rr < 4; ++rr)
          xp[w][g * 4 + rr][nt * 16 + m] = acc[nt][rr];
    }
    barrier_lds();

    // (5) recurrence: 4 steps; wave owns h cols w*16..w*16+15
#pragma unroll
    for (int tl = 0; tl < TC; ++tl) {
      const int tt = c * TC + tl;
      const int rb = tt & 1, pb = rb ^ 1;
      bf16x8 ha0 = *reinterpret_cast<const bf16x8*>(&hbuf[pb][m][g * 8]);
      bf16x8 ha1 = *reinterpret_cast<const bf16x8*>(&hbuf[pb][m][32 + g * 8]);
      f32x4 racc;
#pragma unroll
      for (int r = 0; r < 4; ++r) racc[r] = xp[tl][g * 4 + r][w * 16 + m];
      racc = __builtin_amdgcn_mfma_f32_16x16x32_bf16(ha0, whhf[0], racc, 0, 0, 0);
      racc = __builtin_amdgcn_mfma_f32_16x16x32_bf16(ha1, whhf[1], racc, 0, 0, 0);
      if (g < 2) {
#pragma unroll
        for (int r = 0; r < 4; ++r) {
          const float hv = tanh_fast(racc[r]);
          hbuf[rb][g * 4 + r][w * 16 + m] = f2bf(hv);
          if (tt == TSEQ - 1) xp[0][g * 4 + r][w * 16 + m] = hv;   // final h, f32
        }
      }
      barrier_lds();
    }
  }

  // ---- epilogue: out[b] = sigmoid(h_last . Wout + bout) ----
  if (tid < 64) {
    const int b  = lane >> 3;        // 0..7
    const int j0 = (lane & 7) * 8;   // 0..56
    float s = 0.f;
#pragma unroll
    for (int j = 0; j < 8; ++j) s += xp[0][b][j0 + j] * Wout[j0 + j];
    s += __shfl_xor(s, 1, 64);
    s += __shfl_xor(s, 2, 64);
    s += __shfl_xor(s, 4, 64);
    if ((lane & 7) == 0) {
      const float z = s + bout[0];
      out[b0 + b] = __builtin_amdgcn_rcpf(1.f + exp2f(-z * 1.4426950408889634f));
    }
  }
}

extern "C" void kernel_launch(void* const* d_in, const int* in_sizes, int n_in,
                              void* d_out, int out_size, void* d_ws, size_t ws_size,
                              hipStream_t stream) {
  const float* x    = (const float*)d_in[0];
  const float* Wih  = (const float*)d_in[1];
  const float* Whh  = (const float*)d_in[2];
  const float* bih  = (const float*)d_in[3];
  const float* bhh  = (const float*)d_in[4];
  const float* Wout = (const float*)d_in[5];
  const float* bout = (const float*)d_in[6];
  float* out = (float*)d_out;

  const int B = in_sizes[0] / (TSEQ * DIN);   // 4096
  rnn_fused<<<dim3(B / NB), dim3(256), 0, stream>>>(x, Wih, Whh, bih, bhh, Wout, bout, out);
}